// Round 9
// baseline (1755.676 us; speedup 1.0000x reference)
//
#include <hip/hip_runtime.h>
#include <hip/hip_fp16.h>
#include <cmath>

// Problem constants (reference: B=256, T=512, IN=64, R=2048)
constexpr int kB  = 256;
constexpr int kT  = 512;
constexpr int kIN = 64;
constexpr int kR  = 2048;

constexpr int kBands  = 8;             // m-bands; band = blockIdx&7 -> XCD-local under
                                       // round-robin dispatch (r9/r12-verified)
constexpr int kNB     = 32;            // n-blocks per band
constexpr int kBlocks = kBands * kNB;  // 256 -> 1 block/CU (r10: 2/CU regresses)
constexpr int BM = 32;                 // batches per block
constexpr int BN = 64;                 // n per block (W-band in registers)
constexpr int PFS = 68;                // partial-scratch row stride (words)

typedef _Float16 f16x8 __attribute__((ext_vector_type(8)));
typedef float    f32x4 __attribute__((ext_vector_type(4)));
typedef unsigned long long u64;

#define MFMA16(a, b, c) __builtin_amdgcn_mfma_f32_16x16x32_f16((a), (b), (c), 0, 0, 0)

__device__ __forceinline__ f16x8 cvt8(float4 a, float4 b) {
    f16x8 v;
    v[0] = (_Float16)a.x; v[1] = (_Float16)a.y; v[2] = (_Float16)a.z; v[3] = (_Float16)a.w;
    v[4] = (_Float16)b.x; v[5] = (_Float16)b.y; v[6] = (_Float16)b.z; v[7] = (_Float16)b.w;
    return v;
}

__device__ __forceinline__ unsigned get_xcc_id() {
    unsigned x;
    asm volatile("s_getreg_b32 %0, hwreg(HW_REG_XCC_ID, 0, 8)" : "=s"(x));
    return x & 0xfu;
}

// Fast tanh: 1 - 2/(e^{2x}+1) via hw v_exp_f32. Saturates exactly to +/-1 for
// large |x|; ~1e-6 abs error — negligible vs the 9.8e-3 f16-path absmax.
__device__ __forceinline__ float fast_tanh(float x) {
    float e = __expf(2.0f * x);
    return 1.0f - 2.0f / (e + 1.0f);
}

// One coalesced poll of the band's 32 per-block flags (agent-scope).
__device__ __forceinline__ unsigned poll32(const unsigned* f, int lane, unsigned target) {
    unsigned v = __hip_atomic_load(f + (lane & 31), __ATOMIC_RELAXED, __HIP_MEMORY_SCOPE_AGENT);
    return (unsigned)__ballot(v >= target);
}

// Persistent ESN, r25 = r24 (k-window rotation, CONFIRMED -5%: de-phasing the
// band's 32-way broadcast stream relieves phase-aligned L2 line contention)
// with the permutation upgraded from rotation to AFFINE WALK:
//   w(jj) = (jstart + jj*jstride) & 7, jstart = nb&7,
//   jstride = 2*((nb>>3)&3)+1 in {1,3,5,7} (odd -> bijective mod 8).
//   r24's rotation gave only 8 phases for 32 blocks: the 4 blocks sharing
//   jrot stayed phase-locked over the ENTIRE 16-fragment walk (same start =>
//   same sequence => persistent 4-way same-line collision). With unique
//   (start, stride) per block, same-start blocks collide only at jj=0 and
//   diverge at jj=1 (start+{1,3,5,7} all distinct) — the persistent
//   collision becomes a one-window transient.
//   Permutation applied consistently to wfrag init + af load addresses; all
//   register arrays statically indexed; j-accumulation reorder is fp32
//   reassociation only. Sync topology, publish, epilogue: verbatim r17
//   (r18-r22 ledger: every perturbation there lost).
__global__ __launch_bounds__(512, 2) void esn_persist(
    const float* __restrict__ X,     // [B, T, IN]
    const float* __restrict__ Win,   // [R, IN]
    const float* __restrict__ W,     // [R, R]
    float* __restrict__ out,         // [B, R]
    _Float16* __restrict__ sbuf0,    // swizzled, 1 MB
    _Float16* __restrict__ sbuf1,    // swizzled, 1 MB
    unsigned* __restrict__ flags,    // [8][32], zeroed at launch
    unsigned* __restrict__ xcds)     // [8][32], zeroed at launch
{
    __shared__ __align__(16) float pf[8 * BM * PFS];     // 69632 B
    __shared__ int fast_sh;

    const int tid  = threadIdx.x;
    const int wave = tid >> 6, lane = tid & 63;
    const int quad = lane >> 4, l16 = lane & 15;
    const int q  = wave;             // k-phase: k-slab [256q, 256q+256)
    const int mb = blockIdx.x & 7;   // band (XCD-local heuristic, HW-verified)
    const int nb = blockIdx.x >> 3;  // n-block within band
    const int n0 = nb * BN;
    const int m0 = mb * BM;
    const int jstart = nb & 7;                    // walk start (8 phases)
    const int jstr   = 2 * ((nb >> 3) & 3) + 1;   // walk stride {1,3,5,7}
    unsigned* bandflags = flags + mb * kNB;
    unsigned* bandxcc   = xcds  + mb * kNB;

    if (tid == 0) {
        fast_sh = 0;
        __hip_atomic_store(&bandxcc[nb], get_xcc_id() + 1u,
                           __ATOMIC_RELAXED, __HIP_MEMORY_SCOPE_AGENT);
    }

    // ---- one-time: W-band -> register B-frags (f16), affine-walk order ----
    // wfrag[nt][jj] = W[n0+nt*16+l16][kk*32+quad*8+..], kk = 8q + w(jj)
    f16x8 wfrag[4][8];
    #pragma unroll
    for (int nt = 0; nt < 4; ++nt) {
        const float* wrow = W + (size_t)(n0 + nt * 16 + l16) * kR;
        #pragma unroll
        for (int jj = 0; jj < 8; ++jj) {
            const int jw = (jstart + jj * jstr) & 7;
            const float* p = wrow + (8 * q + jw) * 32 + quad * 8;
            wfrag[nt][jj] = cvt8(*(const float4*)p, *(const float4*)(p + 4));
        }
    }
    // input term: K=64 = 2 k-windows; waves q=0,1 own window q
    f16x8 winfrag[4] = {};
    if (q < 2) {
        #pragma unroll
        for (int nt = 0; nt < 4; ++nt) {
            const float* p = Win + (size_t)(n0 + nt * 16 + l16) * kIN
                           + q * 32 + quad * 8;
            winfrag[nt] = cvt8(*(const float4*)p, *(const float4*)(p + 4));
        }
    }

    // Consumer fragment geometry (swizzled layout, r15-verified):
    // frag (mt, jj) at halfs offset fbase + mt*32768 + w(jj)*512.
    const size_t fbase = ((size_t)(mb * 2) * 64 + 8 * q) * 512 + quad * 128 + l16 * 8;

    // Producer epilogue geometry (r15-verified): 4 contiguous 1-KB runs.
    const int r_   = tid >> 7;            // run 0..3
    const int pos  = (tid & 127) * 4;     // halfs within run
    const int mt_w = r_ >> 1, kwl = r_ & 1;
    const int l16w = (pos >> 3) & 15, qw = pos >> 7, jw_ = pos & 7;
    const int m_loc = mt_w * 16 + l16w;                 // m within band
    const int nn    = kwl * 32 + qw * 8 + jw_;          // n within block (0..63)
    const size_t soff = ((size_t)(mb * 2 + mt_w) * 64 + (nb * 2 + kwl)) * 512 + pos;

    unsigned fastw = 0;   // wave0's register copy of the fast-path predicate

    #pragma unroll 1
    for (int t = 0; t < kT; ++t) {
        // ---- X-frag raw loads for THIS step (latency hidden under sync) ----
        float4 xr[2][2];
        if (q < 2) {
            #pragma unroll
            for (int i = 0; i < 2; ++i) {
                const float* xp = X + ((size_t)(m0 + i * 16 + l16) * kT + t) * kIN
                                + q * 32 + quad * 8;
                xr[i][0] = *(const float4*)xp;
                xr[i][1] = *(const float4*)(xp + 4);
            }
        }

        f32x4 acc[2][4] = {};   // [m-tile][n-tile]

        // ---- recurrent term: disjoint swizzled fragment loads, flat issue ----
        if (t > 0) {
            const _Float16* sprev = (t & 1) ? sbuf0 : sbuf1;
            const unsigned target = (unsigned)t;   // flag >= t <=> s[t-1] published

            if (wave == 0) {
                // whole-band detect; hot-spin first, sleep only if straggling
                unsigned fm = poll32(bandflags, lane, target);
                int spins = 0;
                while (fm != 0xffffffffu) {
                    if (++spins > 16) __builtin_amdgcn_s_sleep(1);
                    fm = poll32(bandflags, lane, target);
                }
                if (t == 1) {
                    // one-time: verify XCD co-location (xcds visible: flag>=1)
                    const unsigned myx = get_xcc_id() + 1u;
                    unsigned px = __hip_atomic_load(bandxcc + (lane & 31),
                                                    __ATOMIC_RELAXED,
                                                    __HIP_MEMORY_SCOPE_AGENT);
                    fastw = (__ballot(px == myx) == ~0ull) ? 1u : 0u;
                    if (lane == 0) fast_sh = (int)fastw;
                }
                if (fastw && t >= 2) {
                    // fast: L1-only invalidate (per-CU, parallel); s lives in
                    // this XCD's shared L2, updated directly by peers' stores.
                    asm volatile("buffer_inv sc0" ::: "memory");
                } else {
                    // safe: full agent acquire (L1+L2 invalidate)
                    __builtin_amdgcn_fence(__ATOMIC_ACQUIRE, "agent");
                }
            }
            __syncthreads();                       // barrier 1 (detect/inv)
            asm volatile("" ::: "memory");

            const _Float16* fp = sprev + fbase;
            f16x8 af[16];   // all 16 fragments: flat issue, max MLP
                            // (af index jj is STATIC; the walk permutation
                            //  lives in the address and wfrag's init pairing)

            #pragma unroll
            for (int jj = 0; jj < 8; ++jj)
                #pragma unroll
                for (int i = 0; i < 2; ++i)
                    af[jj * 2 + i] = *(const f16x8*)(fp + (size_t)i * 32768
                                                     + (size_t)((jstart + jj * jstr) & 7) * 512);
            #pragma unroll
            for (int jj = 0; jj < 8; ++jj) {
                #pragma unroll
                for (int i = 0; i < 2; ++i) {
                    f16x8 av = af[jj * 2 + i];
                    acc[i][0] = MFMA16(av, wfrag[0][jj], acc[i][0]);
                    acc[i][1] = MFMA16(av, wfrag[1][jj], acc[i][1]);
                    acc[i][2] = MFMA16(av, wfrag[2][jj], acc[i][2]);
                    acc[i][3] = MFMA16(av, wfrag[3][jj], acc[i][3]);
                }
            }
        }

        // ---- input term (X loads long done) ----
        if (q < 2) {
            #pragma unroll
            for (int i = 0; i < 2; ++i) {
                f16x8 a = cvt8(xr[i][0], xr[i][1]);
                #pragma unroll
                for (int nt = 0; nt < 4; ++nt)
                    acc[i][nt] = MFMA16(a, winfrag[nt], acc[i][nt]);
            }
        }

        // ---- reduce 8 k-phase partials through LDS, tanh, swizzled store ----
        #pragma unroll
        for (int i = 0; i < 2; ++i)
            #pragma unroll
            for (int nt = 0; nt < 4; ++nt)
                #pragma unroll
                for (int r = 0; r < 4; ++r)
                    pf[q * BM * PFS + (i * 16 + quad * 4 + r) * PFS + nt * 16 + l16]
                        = acc[i][nt][r];
        __syncthreads();                           // barrier 2 (pf)

        f32x4 vs = {};
        #pragma unroll
        for (int p = 0; p < 8; ++p) {
            f32x4 v = *(const f32x4*)&pf[p * BM * PFS + m_loc * PFS + nn];
            vs[0] += v[0]; vs[1] += v[1]; vs[2] += v[2]; vs[3] += v[3];
        }
        float o0 = fast_tanh(vs[0]);
        float o1 = fast_tanh(vs[1]);
        float o2 = fast_tanh(vs[2]);
        float o3 = fast_tanh(vs[3]);

        if (t < kT - 1) {
            _Float16* sout = (t & 1) ? sbuf1 : sbuf0;
            union { u64 u; _Float16 h[4]; } pk;
            pk.h[0] = (_Float16)o0; pk.h[1] = (_Float16)o1;
            pk.h[2] = (_Float16)o2; pk.h[3] = (_Float16)o3;
            u64* dst = (u64*)(sout + soff);        // contiguous across tids
            if (fast_sh) {
                *dst = pk.u;                     // write-back: lands in the
                asm volatile("" ::: "memory");   // XCD's shared L2 (verified)
            } else {
                __hip_atomic_store(dst, pk.u, __ATOMIC_RELAXED,
                                   __HIP_MEMORY_SCOPE_AGENT);  // through to L3
            }
            __builtin_amdgcn_s_waitcnt(0);   // store (and xcc publish) completed
            __syncthreads();                 // barrier 3 (drain; guards pf)
            if (tid == 0)
                __hip_atomic_store(&bandflags[nb], (unsigned)(t + 1),
                                   __ATOMIC_RELAXED, __HIP_MEMORY_SCOPE_AGENT);
        } else {
            // final step: write plain [B, R] fp32 output
            float4 o; o.x = o0; o.y = o1; o.z = o2; o.w = o3;
            *(float4*)(out + (size_t)(m0 + m_loc) * kR + n0 + nn) = o;
        }
    }
}

extern "C" void kernel_launch(void* const* d_in, const int* in_sizes, int n_in,
                              void* d_out, int out_size, void* d_ws, size_t ws_size,
                              hipStream_t stream)
{
    const float* X   = (const float*)d_in[0];  // [B, T, IN]
    const float* Win = (const float*)d_in[1];  // [R, IN]
    const float* W   = (const float*)d_in[2];  // [R, R]
    float* out = (float*)d_out;                // [B, R]

    char* ws = (char*)d_ws;
    _Float16* s0 = (_Float16*)ws;                                  // 1 MB (swizzled)
    _Float16* s1 = (_Float16*)(ws + (size_t)kB * kR * 2);          // 1 MB (swizzled)
    unsigned* flags = (unsigned*)(ws + 2 * (size_t)kB * kR * 2);   // [8][32]
    unsigned* xcds  = flags + kBands * kNB;                        // [8][32]

    hipMemsetAsync(flags, 0, 2 * kBands * kNB * sizeof(unsigned), stream);
    esn_persist<<<kBlocks, 512, 0, stream>>>(X, Win, W, out, s0, s1, flags, xcds);
}